// Round 5
// baseline (428.267 us; speedup 1.0000x reference)
//
#include <hip/hip_runtime.h>
#include <hip/hip_bf16.h>

#define NB 16
#define TT 2048
#define CC 384

typedef short bf16x8 __attribute__((ext_vector_type(8)));
typedef float f32x4 __attribute__((ext_vector_type(4)));

static __device__ __forceinline__ short f2bf(float f) {
  union { __hip_bfloat16 h; short s; } u;
  u.h = __float2bfloat16(f);
  return u.s;
}

// C^-0.5 * log2(e): folded into Q at projection time (attn works in exp2 domain)
#define QSC (0.051031036307982884f * 1.4426950408889634f)

// ---------------------------------------------------------------------------
// x (fp32) -> xb (bf16), flat
// ---------------------------------------------------------------------------
__global__ __launch_bounds__(256)
void conv_x(const float* __restrict__ x, short* __restrict__ xb, int n4) {
  const int i = blockIdx.x * 256 + threadIdx.x;
  if (i < n4) {
    const float4 v = ((const float4*)x)[i];
    short4 o;
    o.x = f2bf(v.x); o.y = f2bf(v.y); o.z = f2bf(v.z); o.w = f2bf(v.w);
    ((short4*)xb)[i] = o;
  }
}

// ---------------------------------------------------------------------------
// W[3] (fp32 [C][H]) -> Wbt (bf16 [3][n=H][k=C])
// ---------------------------------------------------------------------------
__global__ __launch_bounds__(384)
void conv_wt(const float* __restrict__ Wq, const float* __restrict__ Wk,
             const float* __restrict__ Wv, short* __restrict__ Wbt) {
  const int w = blockIdx.x / CC;
  const int n = blockIdx.x % CC;
  const int k = threadIdx.x;
  const float* W = (w == 0) ? Wq : (w == 1) ? Wk : Wv;
  Wbt[((size_t)w * CC + n) * CC + k] = f2bf(W[(size_t)k * CC + n]);
}

// ---------------------------------------------------------------------------
// Fused QKV projection GEMM: [32768 x 384] bf16 x [384 x 1152] bf16 MFMA,
// register-prefetch pipelined. Outputs are written in MFMA FRAGMENT-MAJOR
// layouts so the attention kernel loads fragments as coalesced 1KB b128s:
//   Qf/Kf: [row-tile(16 rows)][ks(12)][quad(4)][l15=row(16)][8 d]  (6144 ea)
//   Vf   : [b][kc(32 keys)][n(24)][quad(4)][l15=d(16)][8 keys]    (12288 ea)
// Epilogues route through LDS (Es) to make the global writes coalesced.
// ---------------------------------------------------------------------------
__global__ __launch_bounds__(256, 3)
void proj_gemm(const short* __restrict__ xb, const short* __restrict__ Wbt,
               short* __restrict__ Qf, short* __restrict__ Kf,
               short* __restrict__ Vf) {
  __shared__ char smem[34816];           // staging (2x10240) U epilogue Es
  short* As = (short*)smem;              // [128][40] shorts
  short* Bs = (short*)(smem + 10240);    // [128][40]
  short* Es = (short*)smem;              // epilogue [128][136]

  const int mt = blockIdx.x & 255;
  const int nt = blockIdx.x >> 8;        // 0..8
  const int wsel = nt / 3;               // 0=Q,1=K,2=V
  const int nc0 = (nt % 3) * 128;
  const int tid = threadIdx.x;
  const int wave = tid >> 6, lane = tid & 63;
  const int l15 = lane & 15, quad = lane >> 4;
  const int wm = (wave & 1) * 64, wn = (wave >> 1) * 64;

  const short* Ab = xb + (size_t)mt * 128 * CC;
  const short* Bb = Wbt + ((size_t)wsel * CC + nc0) * CC;

  f32x4 acc[16];
  #pragma unroll
  for (int i = 0; i < 16; ++i) acc[i] = f32x4{0.f, 0.f, 0.f, 0.f};

  bf16x8 ra[2], rb[2];
  #pragma unroll
  for (int c = 0; c < 2; ++c) {
    const int ci = c * 256 + tid;        // 16B-chunk, 0..511
    ra[c] = *(const bf16x8*)(Ab + (size_t)(ci >> 2) * CC + (ci & 3) * 8);
    rb[c] = *(const bf16x8*)(Bb + (size_t)(ci >> 2) * CC + (ci & 3) * 8);
  }

  for (int kt = 0; kt < 12; ++kt) {
    __syncthreads();
    #pragma unroll
    for (int c = 0; c < 2; ++c) {
      const int ci = c * 256 + tid;
      *(bf16x8*)((char*)As + (ci >> 2) * 80 + (ci & 3) * 16) = ra[c];
      *(bf16x8*)((char*)Bs + (ci >> 2) * 80 + (ci & 3) * 16) = rb[c];
    }
    __syncthreads();
    if (kt < 11) {
      const int k0 = (kt + 1) * 32;
      #pragma unroll
      for (int c = 0; c < 2; ++c) {
        const int ci = c * 256 + tid;
        ra[c] = *(const bf16x8*)(Ab + (size_t)(ci >> 2) * CC + k0 + (ci & 3) * 8);
        rb[c] = *(const bf16x8*)(Bb + (size_t)(ci >> 2) * CC + k0 + (ci & 3) * 8);
      }
    }
    bf16x8 af[4], bf[4];
    #pragma unroll
    for (int i = 0; i < 4; ++i) {
      af[i] = *(const bf16x8*)((char*)As + (wm + i * 16 + l15) * 80 + quad * 16);
      bf[i] = *(const bf16x8*)((char*)Bs + (wn + i * 16 + l15) * 80 + quad * 16);
    }
    #pragma unroll
    for (int i = 0; i < 4; ++i)
      #pragma unroll
      for (int j = 0; j < 4; ++j)
        acc[i * 4 + j] =
            __builtin_amdgcn_mfma_f32_16x16x32_bf16(af[i], bf[j], acc[i * 4 + j], 0, 0, 0);
  }

  __syncthreads();                       // staging done; reuse smem as Es
  if (nt < 6) {
    // ---- Q/K: C -> Es[m][n] (bf16), then frag-major coalesced writes
    const float sc = (nt < 3) ? QSC : 1.0f;
    #pragma unroll
    for (int i = 0; i < 4; ++i)
      #pragma unroll
      for (int j = 0; j < 4; ++j) {
        const f32x4 a = acc[i * 4 + j];
        #pragma unroll
        for (int r = 0; r < 4; ++r)
          Es[(size_t)(wm + i * 16 + quad * 4 + r) * 136 + wn + j * 16 + l15] =
              f2bf(a[r] * sc);
      }
    __syncthreads();
    short* O = (nt < 3) ? Qf : Kf;
    #pragma unroll
    for (int c = 0; c < 8; ++c) {
      const int chunk = c * 256 + tid;          // 0..2047
      const int m  = chunk & 15;
      const int qF = (chunk >> 4) & 3;
      const int ksl = (chunk >> 6) & 3;
      const int tl = chunk >> 8;                // 0..7
      const bf16x8 v = *(const bf16x8*)(Es + (size_t)(tl * 16 + m) * 136 +
                                        ksl * 32 + qF * 8);
      const int Tg = mt * 8 + tl;               // global 16-row tile
      const int ksg = nc0 / 32 + ksl;
      *(bf16x8*)(O + (size_t)Tg * 6144 + ksg * 512 + qF * 128 + m * 8) = v;
    }
  } else {
    // ---- V: C -> Es[d][t] (transposed), then frag-major coalesced writes
    #pragma unroll
    for (int i = 0; i < 4; ++i)
      #pragma unroll
      for (int j = 0; j < 4; ++j) {
        const f32x4 a = acc[i * 4 + j];
        short4 p4;
        p4.x = f2bf(a[0]); p4.y = f2bf(a[1]); p4.z = f2bf(a[2]); p4.w = f2bf(a[3]);
        *(short4*)(Es + (size_t)(wn + j * 16 + l15) * 136 + wm + i * 16 + quad * 4) = p4;
      }
    __syncthreads();
    const int b = mt >> 4;
    #pragma unroll
    for (int c = 0; c < 8; ++c) {
      const int chunk = c * 256 + tid;          // 0..2047
      const int l  = chunk & 15;                // d within n-tile
      const int qF = (chunk >> 4) & 3;          // key-octet
      const int nl = (chunk >> 6) & 7;
      const int kcl = chunk >> 9;               // 0..3
      const bf16x8 v = *(const bf16x8*)(Es + (size_t)(nl * 16 + l) * 136 +
                                        kcl * 32 + qF * 8);
      const int kcg = (mt & 15) * 4 + kcl;      // 32-key chunk within batch
      const int ng  = (nt - 6) * 8 + nl;
      *(bf16x8*)(Vf + ((size_t)(b * 64 + kcg) * 24 + ng) * 512 + qF * 128 + l * 8) = v;
    }
  }
}

// ---------------------------------------------------------------------------
// Flash attention, causal. ONE WAVE PER BLOCK (64 thr), 16 queries/wave,
// 32-key chunks. All K/V/Q fragment loads are coalesced 1KB b128 straight
// from global (frag-major layouts) -> NO LDS staging, NO barriers. Only a
// tiny wave-private LDS buffer for the P C->A layout transpose.
// Grid ordered longest-first; blk%16 = batch (XCD = batch%8) for L2 reuse.
// ---------------------------------------------------------------------------
__global__ __launch_bounds__(64, 2)
void attn_kernel(const short* __restrict__ Qf, const short* __restrict__ Kf,
                 const short* __restrict__ Vf, float* __restrict__ out) {
  __shared__ short pw[16 * 40];             // P transpose buffer (1 wave)

  const int blk = blockIdx.x;
  const int qt  = 127 - (blk >> 4);         // 16-query tile, descending
  const int b   = blk & 15;
  const int lane = threadIdx.x;
  const int l15 = lane & 15, quad = lane >> 4;
  const int q0 = qt * 16;

  // Q fragments: 12 coalesced b128 loads
  bf16x8 qf[12];
  const short* qp = Qf + (size_t)(b * 128 + qt) * 6144 + lane * 8;
  #pragma unroll
  for (int ks = 0; ks < 12; ++ks) qf[ks] = *(const bf16x8*)(qp + ks * 512);

  f32x4 o[24];
  #pragma unroll
  for (int n = 0; n < 24; ++n) o[n] = f32x4{0.f, 0.f, 0.f, 0.f};
  f32x4 lsum = f32x4{0.f, 0.f, 0.f, 0.f};
  float m[4];
  #pragma unroll
  for (int r = 0; r < 4; ++r) m[r] = -INFINITY;

  bf16x8 onesf;
  #pragma unroll
  for (int i = 0; i < 8; ++i) onesf[i] = (short)0x3F80;   // bf16 1.0

  const short* kbase = Kf + (size_t)b * 128 * 6144 + lane * 8;
  const short* vbase = Vf + (size_t)b * 64 * 12288 + lane * 8;
  const int nchunk = (q0 + 47) >> 5;        // keys 0 .. q0+15

  for (int kc = 0; kc < nchunk; ++kc) {
    const int k0 = kc * 32;
    // ---- S = Q K^T (16 q x 32 keys); frags straight from global (L2)
    const short* kt0 = kbase + (size_t)(2 * kc) * 6144;
    f32x4 s0 = f32x4{0.f, 0.f, 0.f, 0.f};
    f32x4 s1 = f32x4{0.f, 0.f, 0.f, 0.f};
    #pragma unroll
    for (int ks = 0; ks < 12; ++ks) {
      const bf16x8 b0 = *(const bf16x8*)(kt0 + ks * 512);
      const bf16x8 b1 = *(const bf16x8*)(kt0 + 6144 + ks * 512);
      s0 = __builtin_amdgcn_mfma_f32_16x16x32_bf16(qf[ks], b0, s0, 0, 0, 0);
      s1 = __builtin_amdgcn_mfma_f32_16x16x32_bf16(qf[ks], b1, s1, 0, 0, 0);
    }
    // ---- causal mask + row max
    const bool domask = (k0 + 31 > q0);
    float mx[4];
    #pragma unroll
    for (int r = 0; r < 4; ++r) {
      float a = s0[r], c = s1[r];
      if (domask) {
        const int qg = q0 + quad * 4 + r;
        if (k0 + l15 > qg)      a = -INFINITY;
        if (k0 + 16 + l15 > qg) c = -INFINITY;
      }
      s0[r] = a; s1[r] = c;
      float v = fmaxf(a, c);
      v = fmaxf(v, __shfl_xor(v, 1));
      v = fmaxf(v, __shfl_xor(v, 2));
      v = fmaxf(v, __shfl_xor(v, 4));
      v = fmaxf(v, __shfl_xor(v, 8));
      mx[r] = v;
    }
    // ---- online softmax (exp2 domain); row-sum via ones-MFMA
    float alpha[4];
    #pragma unroll
    for (int r = 0; r < 4; ++r) {
      const float mn = fmaxf(m[r], mx[r]);
      alpha[r] = exp2f(m[r] - mn);
      m[r] = mn;
      s0[r] = exp2f(s0[r] - mn);
      s1[r] = exp2f(s1[r] - mn);
    }
    const bool need = (alpha[0] < 1.f) | (alpha[1] < 1.f) |
                      (alpha[2] < 1.f) | (alpha[3] < 1.f);
    if (__any(need)) {
      #pragma unroll
      for (int r = 0; r < 4; ++r) lsum[r] *= alpha[r];
      #pragma unroll
      for (int n = 0; n < 24; ++n) {
        #pragma unroll
        for (int r = 0; r < 4; ++r) o[n][r] *= alpha[r];
      }
    }
    // ---- P: C-layout -> A-layout via wave-private LDS (no barrier needed)
    #pragma unroll
    for (int r = 0; r < 4; ++r) {
      pw[(quad * 4 + r) * 40 + l15]      = f2bf(s0[r]);
      pw[(quad * 4 + r) * 40 + 16 + l15] = f2bf(s1[r]);
    }
    const bf16x8 pf = *(const bf16x8*)(pw + l15 * 40 + quad * 8);
    // ---- l += P . 1
    lsum = __builtin_amdgcn_mfma_f32_16x16x32_bf16(pf, onesf, lsum, 0, 0, 0);
    // ---- O += P V; V frags are coalesced 1KB loads
    const short* vp = vbase + (size_t)kc * 12288;
    #pragma unroll
    for (int n = 0; n < 24; ++n) {
      const bf16x8 vf = *(const bf16x8*)(vp + n * 512);
      o[n] = __builtin_amdgcn_mfma_f32_16x16x32_bf16(pf, vf, o[n], 0, 0, 0);
    }
  }

  // ---- epilogue
  float linv[4];
  #pragma unroll
  for (int r = 0; r < 4; ++r) linv[r] = 1.f / lsum[r];
  float* ob = out + ((size_t)b * TT + q0) * CC;
  #pragma unroll
  for (int n = 0; n < 24; ++n) {
    #pragma unroll
    for (int r = 0; r < 4; ++r) {
      ob[(size_t)(quad * 4 + r) * CC + n * 16 + l15] = o[n][r] * linv[r];
    }
  }
}

extern "C" void kernel_launch(void* const* d_in, const int* in_sizes, int n_in,
                              void* d_out, int out_size, void* d_ws, size_t ws_size,
                              hipStream_t stream) {
  const float* x  = (const float*)d_in[0];
  const float* Wq = (const float*)d_in[1];
  const float* Wk = (const float*)d_in[2];
  const float* Wv = (const float*)d_in[3];
  float* out = (float*)d_out;

  const size_t QS = (size_t)NB * TT * CC;     // 12.58M elems
  short* Qf = (short*)d_ws;
  short* Kf = Qf + QS;
  short* Vf = Kf + QS;                        // ws: 75.5 MB

  // bf16 staging lives in d_out (50 MB fp32) until attn overwrites it
  short* xb  = (short*)d_out;                 // 25.2 MB
  short* Wbt = xb + QS;                       // 0.9 MB

  hipLaunchKernelGGL(conv_x, dim3((int)(QS / 4 / 256)), dim3(256), 0, stream,
                     x, xb, (int)(QS / 4));
  hipLaunchKernelGGL(conv_wt, dim3(3 * CC), dim3(CC), 0, stream, Wq, Wk, Wv, Wbt);
  hipLaunchKernelGGL(proj_gemm, dim3(256 * 9), dim3(256), 0, stream,
                     xb, Wbt, Qf, Kf, Vf);
  hipLaunchKernelGGL(attn_kernel, dim3(NB * TT / 16), dim3(64), 0, stream,
                     Qf, Kf, Vf, out);
}